// Round 8
// baseline (338.640 us; speedup 1.0000x reference)
//
#include <hip/hip_runtime.h>
#include <hip/hip_bf16.h>
#include <stdint.h>

// ---------------------------------------------------------------------------
// Cosine similarity: C[n][m] = <z_n/||z_n||, cm_m/||cm_m||>
// M=32768 rows z, Ncls=1001 rows cm, K=512, out fp32 [M][Ncls].
// Pass 1 (tiny): normalize cm rows -> bf16 bn [Npad=1024][512] in d_ws (1 MB).
// Pass 2 (fused): GEMM C = bf16(z) * bn^T scaled by 1/||z_row||.
//
// R8 = R7's gemm schedule fused back into the one-pass kernel:
//   - 64x256 tile, 256 thr (4 waves of 64x64), 3 blocks/CU: three
//     INDEPENDENT 4-wave barrier groups per CU cover each other's drains
//     (R5's 2x8-wave lockstep was the diagnosed structural cost).
//   - Frags-to-regs-first: read all 16 fragments of tile t into VGPRs,
//     barrier, then stage tile t+1 (B gl_lds x8, A convert+ds_write) UNDER
//     the 16 MFMAs. Single-buffered LDS stays race-free (reads are in regs
//     before the overwrite). Conversion VALU now overlaps MFMA.
//   - A-path unchanged from R5: fp32 -> regs (prefetch distance 2) -> ssq
//     -> f2bf -> ds_write; norms reduced once after the loop.
//   - setprio(1) around MFMA cluster (T5: 3 independent blocks = diversity).
//   - Register budget: acc 64 + frags 64 + prefetch 16 + addr ~20 <= 170
//     -> __launch_bounds__(256,3) pins 3 waves/SIMD.
// Record: R0 86.6 | R1 103 | R3 100 | R4 1150 (NT stores) | R5 83.5 (best
// fused) | R6 132 (tile too small) | R7 two-pass: gemm ~77 but prepass ~25
// net loss + 525 MB harness re-poison on big ws. Schedule kept, prepass cut.
// Workspace need: 1024*512*2 B = 1 MB.
// ---------------------------------------------------------------------------

typedef short short8 __attribute__((ext_vector_type(8)));
typedef float f32x16 __attribute__((ext_vector_type(16)));

#define KDIM 512
#define BK 64
#define NT 8              // K-tiles = KDIM/BK

__device__ __forceinline__ unsigned short f2bf(float f) {
  uint32_t u = __float_as_uint(f);
  u += 0x7FFFu + ((u >> 16) & 1u);   // round-to-nearest-even
  return (unsigned short)(u >> 16);
}

#define MFMA(a, b, c) __builtin_amdgcn_mfma_f32_32x32x16_bf16((a), (b), (c), 0, 0, 0)

// One wave per cm row; rows >= Ncls written as zeros (GEMM B-side pad).
__global__ __launch_bounds__(256) void normalize_cm_kernel(
    const float* __restrict__ cm, unsigned short* __restrict__ bn,
    int Ncls, int Npad) {
  int r = blockIdx.x * 4 + (threadIdx.x >> 6);
  int lane = threadIdx.x & 63;
  if (r >= Npad) return;
  unsigned short* dst = bn + (size_t)r * KDIM;
  if (r >= Ncls) {
    uint2 zv = make_uint2(0u, 0u);
    *(uint2*)(dst + lane * 4) = zv;
    *(uint2*)(dst + 256 + lane * 4) = zv;
    return;
  }
  const float4* s4 = (const float4*)(cm + (size_t)r * KDIM);
  float4 x0 = s4[lane];
  float4 x1 = s4[lane + 64];
  float s = x0.x * x0.x + x0.y * x0.y + x0.z * x0.z + x0.w * x0.w +
            x1.x * x1.x + x1.y * x1.y + x1.z * x1.z + x1.w * x1.w;
#pragma unroll
  for (int off = 32; off > 0; off >>= 1) s += __shfl_xor(s, off, 64);
  float scale = 1.0f / fmaxf(sqrtf(s), 1e-8f);

  union { unsigned short u[4]; uint2 v; } p0, p1;
  p0.u[0] = f2bf(x0.x * scale); p0.u[1] = f2bf(x0.y * scale);
  p0.u[2] = f2bf(x0.z * scale); p0.u[3] = f2bf(x0.w * scale);
  p1.u[0] = f2bf(x1.x * scale); p1.u[1] = f2bf(x1.y * scale);
  p1.u[2] = f2bf(x1.z * scale); p1.u[3] = f2bf(x1.w * scale);
  *(uint2*)(dst + lane * 4) = p0.v;
  *(uint2*)(dst + 256 + lane * 4) = p1.v;
}

// Fused: C = bf16(Z) * B^T, rows scaled by 1/max(||Z_row||, 1e-8).
// Z: [M][512] fp32, B: [Npad][512] bf16 bits, C: [M][Ncls] f32.
// Tile 64x256, 4 waves (each 64x64: shared 64 A-rows, own 64 B-cols).
__global__ __launch_bounds__(256, 3) void gemm_fused_kernel(
    const float* __restrict__ Z,
    const unsigned short* __restrict__ B,
    float* __restrict__ C, int M, int Ncls) {
  __shared__ unsigned short As[64 * BK];    // 8 KB
  __shared__ unsigned short Bs[256 * BK];   // 32 KB
  __shared__ float ns[64];                  // row ||z||^2

  const int tid = threadIdx.x;
  const int wave = tid >> 6;       // 0..3
  const int lane = tid & 63;

  // XCD-chunked bijective swizzle (nwg == 2048, % 8 == 0); N-tile fastest
  // within an XCD -> the 4 N-siblings sharing an A-panel run consecutively.
  const int nwg = gridDim.x;
  const int cpx = nwg >> 3;
  const int bid = blockIdx.x;
  const int wg = (bid & 7) * cpx + (bid >> 3);
  const int m0 = (wg >> 2) * 64;   // 512 M-tiles
  const int n0 = (wg & 3) * 256;   // 4 N-tiles

  const int wn = wave * 64;        // wave's N offset

  // Chunk = 8 rows x 64 cols. Lane l: row l>>3, source unit (l&7)^((l>>3)&7)
  // -> LDS[row][u'] holds source unit u'^(row&7) (proven conflict-free).
  const int l3 = lane >> 3;
  const int su = (lane & 7) ^ (l3 & 7);

  // A: 8 chunks total, 2 per wave (fp32 source, converted in-register).
  const int chA = wave * 2;
  const float* Ag0 = Z + (size_t)(m0 + chA * 8 + l3) * KDIM + su * 8;
  const float* Ag1 = Z + (size_t)(m0 + (chA + 1) * 8 + l3) * KDIM + su * 8;
  unsigned short* const Al0 = &As[chA * 512 + lane * 8];
  unsigned short* const Al1 = &As[(chA + 1) * 512 + lane * 8];

  // B: 32 chunks total, 8 per wave (async bf16 straight to LDS).
  const unsigned short* Bgp[8];
  unsigned short* Blp[8];
#pragma unroll
  for (int c = 0; c < 8; ++c) {
    int cb = wave * 8 + c;
    Bgp[c] = B + (size_t)(n0 + cb * 8 + l3) * KDIM + su * 8;
    Blp[c] = &Bs[cb * 512 + lane * 8];
  }

  const int fm = lane & 31;        // fragment row (A: m, B: n)
  const int kh = lane >> 5;        // k-half
  const int fx = fm & 7;           // swizzle phase

  f32x16 acc[2][2] = {};
  float rs0 = 0.0f, rs1 = 0.0f;    // per-thread partial row ssq

  float4 p00, p01, p10, p11;       // A prefetch regs (tile t+1)

  // ---- prologue: stage tile 0 (A convert + B gl_lds), prefetch A(1).
  {
    float4 q00 = *(const float4*)(Ag0);
    float4 q01 = *(const float4*)(Ag0 + 4);
    float4 q10 = *(const float4*)(Ag1);
    float4 q11 = *(const float4*)(Ag1 + 4);
#pragma unroll
    for (int c = 0; c < 8; ++c)
      __builtin_amdgcn_global_load_lds(
          (const __attribute__((address_space(1))) void*)(Bgp[c]),
          (__attribute__((address_space(3))) void*)Blp[c], 16, 0, 0);
    rs0 += q00.x * q00.x + q00.y * q00.y + q00.z * q00.z + q00.w * q00.w +
           q01.x * q01.x + q01.y * q01.y + q01.z * q01.z + q01.w * q01.w;
    rs1 += q10.x * q10.x + q10.y * q10.y + q10.z * q10.z + q10.w * q10.w +
           q11.x * q11.x + q11.y * q11.y + q11.z * q11.z + q11.w * q11.w;
    union { unsigned short u[8]; uint4 v; } pk;
    pk.u[0] = f2bf(q00.x); pk.u[1] = f2bf(q00.y);
    pk.u[2] = f2bf(q00.z); pk.u[3] = f2bf(q00.w);
    pk.u[4] = f2bf(q01.x); pk.u[5] = f2bf(q01.y);
    pk.u[6] = f2bf(q01.z); pk.u[7] = f2bf(q01.w);
    *(uint4*)Al0 = pk.v;
    pk.u[0] = f2bf(q10.x); pk.u[1] = f2bf(q10.y);
    pk.u[2] = f2bf(q10.z); pk.u[3] = f2bf(q10.w);
    pk.u[4] = f2bf(q11.x); pk.u[5] = f2bf(q11.y);
    pk.u[6] = f2bf(q11.z); pk.u[7] = f2bf(q11.w);
    *(uint4*)Al1 = pk.v;
    p00 = *(const float4*)(Ag0 + BK);
    p01 = *(const float4*)(Ag0 + BK + 4);
    p10 = *(const float4*)(Ag1 + BK);
    p11 = *(const float4*)(Ag1 + BK + 4);
  }
  __syncthreads();   // tile 0 staged (vmcnt+lgkm drained by compiler)

  for (int t = 0; t < NT; ++t) {
    // 1) Read ALL fragments of tile t into registers (16 x ds_read_b128).
    short8 ra0[4], ra1[4], rb0[4], rb1[4];
#pragma unroll
    for (int ks = 0; ks < 4; ++ks) {
      int u = ((ks << 1) | kh) ^ fx;
      ra0[ks] = *(const short8*)&As[fm * BK + u * 8];
      ra1[ks] = *(const short8*)&As[(32 + fm) * BK + u * 8];
      rb0[ks] = *(const short8*)&Bs[(wn + fm) * BK + u * 8];
      rb1[ks] = *(const short8*)&Bs[(wn + 32 + fm) * BK + u * 8];
    }
    if (t + 1 < NT) {
      // 2) Barrier: every wave's LDS reads landed in regs -> safe to overwrite.
      __syncthreads();
      // 3) Stage tile t+1 under the MFMAs: B async, A convert from prefetch.
      const int k1 = (t + 1) * BK;
#pragma unroll
      for (int c = 0; c < 8; ++c)
        __builtin_amdgcn_global_load_lds(
            (const __attribute__((address_space(1))) void*)(Bgp[c] + k1),
            (__attribute__((address_space(3))) void*)Blp[c], 16, 0, 0);
      rs0 += p00.x * p00.x + p00.y * p00.y + p00.z * p00.z + p00.w * p00.w +
             p01.x * p01.x + p01.y * p01.y + p01.z * p01.z + p01.w * p01.w;
      rs1 += p10.x * p10.x + p10.y * p10.y + p10.z * p10.z + p10.w * p10.w +
             p11.x * p11.x + p11.y * p11.y + p11.z * p11.z + p11.w * p11.w;
      union { unsigned short u[8]; uint4 v; } pk;
      pk.u[0] = f2bf(p00.x); pk.u[1] = f2bf(p00.y);
      pk.u[2] = f2bf(p00.z); pk.u[3] = f2bf(p00.w);
      pk.u[4] = f2bf(p01.x); pk.u[5] = f2bf(p01.y);
      pk.u[6] = f2bf(p01.z); pk.u[7] = f2bf(p01.w);
      *(uint4*)Al0 = pk.v;
      pk.u[0] = f2bf(p10.x); pk.u[1] = f2bf(p10.y);
      pk.u[2] = f2bf(p10.z); pk.u[3] = f2bf(p10.w);
      pk.u[4] = f2bf(p11.x); pk.u[5] = f2bf(p11.y);
      pk.u[6] = f2bf(p11.z); pk.u[7] = f2bf(p11.w);
      *(uint4*)Al1 = pk.v;
      // Prefetch A(t+2) into regs (flies across the next barrier).
      if (t + 2 < NT) {
        const int k2 = (t + 2) * BK;
        p00 = *(const float4*)(Ag0 + k2);
        p01 = *(const float4*)(Ag0 + k2 + 4);
        p10 = *(const float4*)(Ag1 + k2);
        p11 = *(const float4*)(Ag1 + k2 + 4);
      }
    }
    // 4) MFMA from registers (covers the staging flight above).
    __builtin_amdgcn_s_setprio(1);
#pragma unroll
    for (int ks = 0; ks < 4; ++ks) {
      acc[0][0] = MFMA(ra0[ks], rb0[ks], acc[0][0]);
      acc[0][1] = MFMA(ra0[ks], rb1[ks], acc[0][1]);
      acc[1][0] = MFMA(ra1[ks], rb0[ks], acc[1][0]);
      acc[1][1] = MFMA(ra1[ks], rb1[ks], acc[1][1]);
    }
    __builtin_amdgcn_s_setprio(0);
    // 5) Barrier: tile t+1 fully landed (vmcnt+lgkm drained by compiler).
    if (t + 1 < NT) __syncthreads();
  }

  // Finish row norms: reduce across the 8 lanes sharing each row, publish.
#pragma unroll
  for (int off = 1; off < 8; off <<= 1) {
    rs0 += __shfl_xor(rs0, off, 64);
    rs1 += __shfl_xor(rs1, off, 64);
  }
  if ((lane & 7) == 0) {
    ns[chA * 8 + l3] = rs0;       // rows of chunk chA
    ns[chA * 8 + 8 + l3] = rs1;   // rows of chunk chA+1
  }
  __syncthreads();

  // Epilogue: C = acc * 1/max(||z_row||, eps). All waves share rows 0..63.
  // C/D layout (32x32): col = lane&31, row = (r&3) + 8*(r>>2) + 4*(lane>>5).
  const int cn = lane & 31;
  const int ch4 = kh * 4;
#pragma unroll
  for (int mi = 0; mi < 2; ++mi) {
    float rn[16];
#pragma unroll
    for (int q = 0; q < 4; ++q) {
      float4 n4 = *(const float4*)&ns[mi * 32 + q * 8 + ch4];
      rn[q * 4 + 0] = 1.0f / fmaxf(sqrtf(n4.x), 1e-8f);
      rn[q * 4 + 1] = 1.0f / fmaxf(sqrtf(n4.y), 1e-8f);
      rn[q * 4 + 2] = 1.0f / fmaxf(sqrtf(n4.z), 1e-8f);
      rn[q * 4 + 3] = 1.0f / fmaxf(sqrtf(n4.w), 1e-8f);
    }
#pragma unroll
    for (int ni = 0; ni < 2; ++ni) {
      int n = n0 + wn + ni * 32 + cn;
      if (n < Ncls) {
        size_t base = (size_t)(m0 + mi * 32 + ch4) * (size_t)Ncls + n;
#pragma unroll
        for (int r = 0; r < 16; ++r) {
          int row = (r & 3) + 8 * (r >> 2);
          C[base + (size_t)row * Ncls] = acc[mi][ni][r] * rn[r];
        }
      }
    }
  }
}

extern "C" void kernel_launch(void* const* d_in, const int* in_sizes, int n_in,
                              void* d_out, int out_size, void* d_ws, size_t ws_size,
                              hipStream_t stream) {
  const float* z  = (const float*)d_in[0];
  const float* cm = (const float*)d_in[1];
  float* out = (float*)d_out;

  const int M    = in_sizes[0] / KDIM;                 // 32768
  const int Ncls = in_sizes[1] / KDIM;                 // 1001
  const int Npad = ((Ncls + 255) / 256) * 256;         // 1024

  unsigned short* bn = (unsigned short*)d_ws;          // 1 MB

  normalize_cm_kernel<<<Npad / 4, 256, 0, stream>>>(cm, bn, Ncls, Npad);

  // 1-D grid, XCD swizzle in-kernel: (M/64) x (Npad/256) = 512 x 4 = 2048.
  const int nwg = (M / 64) * (Npad / 256);             // 2048, % 8 == 0
  gemm_fused_kernel<<<dim3(nwg), 256, 0, stream>>>(z, bn, out, M, Ncls);
}